// Round 18
// baseline (285.505 us; speedup 1.0000x reference)
//
#include <hip/hip_runtime.h>
#include <hip/hip_cooperative_groups.h>
namespace cg = cooperative_groups;

typedef unsigned short u16;
typedef __bf16 bf16x8 __attribute__((ext_vector_type(8)));
typedef float  f32x4  __attribute__((ext_vector_type(4)));
typedef unsigned int   u32x4 __attribute__((ext_vector_type(4)));
typedef unsigned short u16x4 __attribute__((ext_vector_type(4)));

#define DEV __device__ __forceinline__

#define NB   16
#define TT   512
#define DD   256
#define HH   4
#define DKH  64
#define NLANG 10
#define FFD  1024

DEV u16 f2bf(float f) {
  unsigned int u = __builtin_bit_cast(unsigned int, f);
  return (u16)((u + 0x7fffu + ((u >> 16) & 1u)) >> 16);
}

DEV float bf2f(u16 u) {
  unsigned int x = ((unsigned int)u) << 16;
  return __builtin_bit_cast(float, x);
}

DEV f32x4 zero4() { f32x4 z; z[0]=0.f; z[1]=0.f; z[2]=0.f; z[3]=0.f; return z; }

typedef __attribute__((address_space(1))) const unsigned int g_as1;
typedef __attribute__((address_space(3))) unsigned int l_as3;
DEV void load_lds16(const void* g, void* l) {
  __builtin_amdgcn_global_load_lds((g_as1*)g, (l_as3*)l, 16, 0, 0);
}

DEV bf16x8 lds_frag(const u16* lds, int row, int slot) {
  return *(const bf16x8*)(lds + row * 64 + ((slot ^ (row & 7)) << 3));
}

// 128x128 GEMM tile, 256-thr semantics (tid in [0,256)); barriers hit by ALL 512.
DEV void gemm128(const u16* __restrict__ A, const u16* __restrict__ W, int K,
                 int m0, int n0, u16* Alds, u16* Blds, f32x4 acc[4][4],
                 bool valid, int tid) {
  const int lane = tid & 63, wave = tid >> 6;
  const int wm = wave >> 1, wn = wave & 1;
  const int l15 = lane & 15, lhi = lane >> 4;
  const int lr = lane >> 3, lsl = lane & 7;
  const u16* srcA[4]; const u16* srcB[4];
#pragma unroll
  for (int j = 0; j < 4; ++j) {
    const int r = wave * 32 + j * 8 + lr;
    srcA[j] = A + (size_t)(m0 + r) * K + ((lsl ^ (r & 7)) << 3);
    srcB[j] = W + (size_t)(n0 + r) * K + ((lsl ^ (r & 7)) << 3);
  }
  for (int k0 = 0; k0 < K; k0 += 64) {
    if (valid) {
#pragma unroll
      for (int j = 0; j < 4; ++j) {
        load_lds16(srcA[j] + k0, Alds + (wave * 32 + j * 8) * 64);
        load_lds16(srcB[j] + k0, Blds + (wave * 32 + j * 8) * 64);
      }
    }
    __syncthreads();
#pragma unroll
    for (int ks = 0; ks < 2; ++ks) {
      const int slot = ks * 4 + lhi;
      bf16x8 af[4], bfr[4];
#pragma unroll
      for (int m = 0; m < 4; ++m)
        af[m] = lds_frag(Alds, wm * 64 + m * 16 + l15, slot);
#pragma unroll
      for (int n = 0; n < 4; ++n)
        bfr[n] = lds_frag(Blds, wn * 64 + n * 16 + l15, slot);
#pragma unroll
      for (int m = 0; m < 4; ++m)
#pragma unroll
        for (int n = 0; n < 4; ++n)
          acc[m][n] = __builtin_amdgcn_mfma_f32_16x16x32_bf16(af[m], bfr[n], acc[m][n], 0, 0, 0);
    }
    __syncthreads();
  }
}

// GEMM(Mtile32 x N256) + residual + row-LN; 512-thr; single-buffered (R17: occupancy > pipelining)
DEV void gemm_ln_stage(const u16* __restrict__ A, const u16* __restrict__ Wt,
                       const float* __restrict__ bias, const u16* __restrict__ res,
                       void* outf, u16* outbf, const float* __restrict__ g,
                       const float* __restrict__ be, const int* __restrict__ lids,
                       int K, int bx, char* smem, int tid512, bool FINAL) {
  u16* Alds = (u16*)smem;                       // 4KB
  u16* Blds = (u16*)(smem + 4096);              // 32KB
  float* Sred = (float*)(smem + 36864);         // [2][4][16]
  float* SSred = Sred + 128;
  const int b = bx >> 4;
  const int z = lids[b];
  const int m0 = (bx & 15) * 32;
  const int lane = tid512 & 63, wave = tid512 >> 6;
  const int l15 = lane & 15, lhi = lane >> 4;
  const int lr = lane >> 3, lsl = lane & 7;
  const u16* Ab = A + (size_t)b * TT * K;
  const u16* Wb = Wt + (size_t)z * 256 * K;
  const u16* srcA = Ab;
  if (wave < 4) {
    const int rA = wave * 8 + lr;
    srcA = Ab + (size_t)(m0 + rA) * K + ((lsl ^ (rA & 7)) << 3);
  }
  const u16* srcB[4];
#pragma unroll
  for (int j = 0; j < 4; ++j) {
    const int rB = wave * 32 + j * 8 + lr;
    srcB[j] = Wb + (size_t)rB * K + ((lsl ^ (rB & 7)) << 3);
  }
  f32x4 acc[4];
#pragma unroll
  for (int n = 0; n < 4; ++n) acc[n] = zero4();
  for (int k0 = 0; k0 < K; k0 += 64) {
    if (wave < 4) load_lds16(srcA + k0, Alds + (wave * 8) * 64);
#pragma unroll
    for (int j = 0; j < 4; ++j)
      load_lds16(srcB[j] + k0, Blds + (wave * 32 + j * 8) * 64);
    __syncthreads();
#pragma unroll
    for (int ks = 0; ks < 2; ++ks) {
      const int slot = ks * 4 + lhi;
      bf16x8 af = lds_frag(Alds, (wave >> 2) * 16 + l15, slot);
#pragma unroll
      for (int n = 0; n < 4; ++n) {
        bf16x8 bf = lds_frag(Blds, (wave & 3) * 64 + n * 16 + l15, slot);
        acc[n] = __builtin_amdgcn_mfma_f32_16x16x32_bf16(af, bf, acc[n], 0, 0, 0);
      }
    }
    __syncthreads();
  }
  const int rbase = m0 + (wave >> 2) * 16;
  const int cq = (wave & 3) * 64;
  float bv[4], gv[4], bev[4];
#pragma unroll
  for (int n = 0; n < 4; ++n) {
    const int col = cq + n * 16 + l15;
    bv[n]  = bias[(size_t)z * 256 + col];
    gv[n]  = g[(size_t)z * 256 + col];
    bev[n] = be[(size_t)z * 256 + col];
  }
  float v[4][4];
  float sr[4] = {0.f, 0.f, 0.f, 0.f}, ssr[4] = {0.f, 0.f, 0.f, 0.f};
#pragma unroll
  for (int n = 0; n < 4; ++n) {
#pragma unroll
    for (int r = 0; r < 4; ++r) {
      const size_t idx = ((size_t)b * TT + rbase + lhi * 4 + r) * 256 + cq + n * 16 + l15;
      float t = acc[n][r] + bv[n] + bf2f(res[idx]);
      v[n][r] = t;
      sr[r] += t;
      ssr[r] += t * t;
    }
  }
#pragma unroll
  for (int d = 1; d < 16; d <<= 1)
#pragma unroll
    for (int r = 0; r < 4; ++r) { sr[r] += __shfl_xor(sr[r], d); ssr[r] += __shfl_xor(ssr[r], d); }
  if (l15 == 0) {
#pragma unroll
    for (int r = 0; r < 4; ++r) {
      const int si = ((wave >> 2) * 4 + (wave & 3)) * 16 + lhi * 4 + r;
      Sred[si] = sr[r];
      SSred[si] = ssr[r];
    }
  }
  __syncthreads();
#pragma unroll
  for (int r = 0; r < 4; ++r) {
    float tot = 0.f, tss = 0.f;
#pragma unroll
    for (int qd = 0; qd < 4; ++qd) {
      const int si = ((wave >> 2) * 4 + qd) * 16 + lhi * 4 + r;
      tot += Sred[si];
      tss += SSred[si];
    }
    const float mean = tot * (1.0f / 256.0f);
    const float var  = tss * (1.0f / 256.0f) - mean * mean;
    const float rstd = rsqrtf(var + 1e-12f);
#pragma unroll
    for (int n = 0; n < 4; ++n) {
      const size_t idx = ((size_t)b * TT + rbase + lhi * 4 + r) * 256 + cq + n * 16 + l15;
      const float ln = (v[n][r] - mean) * rstd * gv[n] + bev[n];
      if (FINAL) {
        ((float*)outf)[idx] = ln;
      } else {
        ((u16*)outf)[idx] = f2bf(v[n][r]);
        outbf[idx] = f2bf(ln);
      }
    }
  }
  __syncthreads();
}

// ================= persistent cooperative kernel: all 6 stages =================
__global__ __launch_bounds__(512, 2) void mega_kernel(
    const float* __restrict__ x, const int* __restrict__ xlen, const int* __restrict__ lids,
    const float* __restrict__ Wq, const float* __restrict__ bq,
    const float* __restrict__ Wk, const float* __restrict__ bk,
    const float* __restrict__ Wv, const float* __restrict__ bv,
    const float* __restrict__ Wo, const float* __restrict__ bo,
    const float* __restrict__ W1, const float* __restrict__ b1,
    const float* __restrict__ W2, const float* __restrict__ b2,
    const float* __restrict__ g1, const float* __restrict__ be1,
    const float* __restrict__ g2, const float* __restrict__ be2,
    const float* __restrict__ gf, const float* __restrict__ bef,
    u16* wtq, u16* wtk, u16* wtv, u16* wto, u16* wt1, u16* wt2,
    u16* h0, u16* hc, u16* hn, u16* qb, u16* kb, u16* vtb, u16* ctx, u16* ffn,
    float* out) {
  __shared__ char smem[69632];
  cg::grid_group grid = cg::this_grid();
  const int tid512 = threadIdx.x;
  const int sub = tid512 >> 8;
  const int tid = tid512 & 255;
  const int bx = blockIdx.x;   // 0..255

  // ---------- stage 0: weight transpose/convert + embed+LN1 (5888 units) ----------
  {
    u16 (*tile)[33] = (u16 (*)[33])(smem + sub * (64 * 33 * 2));
    for (int it = 0; it < 12; ++it) {
      const int unit = it * 512 + bx * 2 + sub;
      const bool isT = unit < 3840;
      const bool isE = !isT && unit < 5888;
      const float* src = nullptr; u16* dst = nullptr;
      int R = 256, C = 256, z = 0, r0 = 0, c0 = 0;
      bool used = false;
      if (isT) {
        if (unit < 1280) {
          const int w = unit / 320, rem = unit % 320;
          src = (w == 0) ? Wq : (w == 1) ? Wk : (w == 2) ? Wv : Wo;
          dst = (w == 0) ? wtq : (w == 1) ? wtk : (w == 2) ? wtv : wto;
          R = 256; C = 256; z = rem >> 5;
          const int rc = rem & 31; r0 = (rc >> 3) * 64; c0 = (rc & 7) * 32;
        } else if (unit < 2560) {
          const int rem = unit - 1280; src = W1; dst = wt1; R = 256; C = 1024;
          z = rem >> 7; const int rc = rem & 127; r0 = (rc >> 5) * 64; c0 = (rc & 31) * 32;
        } else {
          const int rem = unit - 2560; src = W2; dst = wt2; R = 1024; C = 256;
          z = rem >> 7; const int rc = rem & 127; r0 = (rc >> 3) * 64; c0 = (rc & 7) * 32;
        }
#pragma unroll
        for (int i = 0; i < NB; ++i) used |= (lids[i] == z);
      }
      const int tx = tid & 31, ty = tid >> 5;
      if (isT && used) {
        const float* s = src + (size_t)z * R * C;
#pragma unroll
        for (int rr = 0; rr < 8; ++rr) {
          const int r = ty + rr * 8;
          tile[r][tx] = f2bf(s[(size_t)(r0 + r) * C + c0 + tx]);
        }
      }
      __syncthreads();
      if (isT && used) {
        u16* d = dst + (size_t)z * R * C;
#pragma unroll
        for (int rr = 0; rr < 4; ++rr) {
          const int cc = ty + rr * 8;
          const unsigned int lo = tile[tx * 2][cc], hi = tile[tx * 2 + 1][cc];
          *(unsigned int*)(d + (size_t)(c0 + cc) * R + r0 + tx * 2) = lo | (hi << 16);
        }
      }
      if (isE) {
        const int wave = tid >> 6, lane = tid & 63;
        const int row = (unit - 3840) * 4 + wave;
        const int b = row >> 9, t = row & 511;
        const int z2 = lids[b];
        const int c0e = lane * 4;
        const float4 xv = *(const float4*)(x + (size_t)row * DD + c0e);
        const float kPE = -9.21034037197618f / 256.0f;
        float div0 = __expf(kPE * (float)c0e);
        float div1 = __expf(kPE * (float)(c0e + 2));
        float a0 = div0 * (float)t, a1 = div1 * (float)t;
        float h[4];
        h[0] = xv.x * 16.0f + __sinf(a0);
        h[1] = xv.y * 16.0f + __cosf(a0);
        h[2] = xv.z * 16.0f + __sinf(a1);
        h[3] = xv.w * 16.0f + __cosf(a1);
        float s = h[0] + h[1] + h[2] + h[3];
        float ss = h[0]*h[0] + h[1]*h[1] + h[2]*h[2] + h[3]*h[3];
#pragma unroll
        for (int d = 1; d < 64; d <<= 1) { s += __shfl_xor(s, d); ss += __shfl_xor(ss, d); }
        float mean = s * (1.0f / 256.0f);
        float var  = ss * (1.0f / 256.0f) - mean * mean;
        float rstd = rsqrtf(var + 1e-12f);
        u16x4 h0v;
#pragma unroll
        for (int j = 0; j < 4; ++j) h0v[j] = f2bf(h[j]);
        *(u16x4*)(h0 + (size_t)row * DD + c0e) = h0v;
        u16x4 o;
#pragma unroll
        for (int j = 0; j < 4; ++j)
          o[j] = f2bf((h[j] - mean) * rstd * g1[z2 * DD + c0e + j] + be1[z2 * DD + c0e + j]);
        *(u16x4*)(hn + (size_t)row * DD + c0e) = o;
      }
      __syncthreads();
    }
  }
  grid.sync();

  // ---------- stage 1: QKV (384 units of 256 thr; 2 per block) ----------
  {
    const int unit = bx * 2 + sub;
    const bool valid = unit < 384;
    u16* Alds = (u16*)(smem + sub * 32768);
    u16* Blds = Alds + 128 * 64;
    const int nx = unit & 1, my = (unit >> 1) & 3, bz = unit >> 3;
    const int b = bz & 15, which = (bz >> 4) & 3;
    const int z = lids[b];
    const u16* W = (which == 0) ? wtq : (which == 1) ? wtk : wtv;
    const float* bias = (which == 0) ? bq : (which == 1) ? bk : bv;
    const int m0 = my * 128, n0 = nx * 128;
    f32x4 acc[4][4];
#pragma unroll
    for (int i = 0; i < 4; ++i)
#pragma unroll
      for (int j = 0; j < 4; ++j) acc[i][j] = zero4();
    gemm128(hn + (size_t)b * TT * DD, W + (size_t)z * DD * DD, DD, m0, n0,
            Alds, Blds, acc, valid, tid);
    if (valid) {
      const int lane = tid & 63, wave = tid >> 6;
      const int wm = wave >> 1, wn = wave & 1;
      const int l15 = lane & 15, lhi = lane >> 4;
      float bvv[4];
#pragma unroll
      for (int n = 0; n < 4; ++n) bvv[n] = bias[(size_t)z * DD + n0 + wn * 64 + n * 16 + l15];
      if (which < 2) {
        u16* outp = (which == 0) ? qb : kb;
#pragma unroll
        for (int m = 0; m < 4; ++m) {
          const int grow = m0 + wm * 64 + m * 16 + lhi * 4;
#pragma unroll
          for (int n = 0; n < 4; ++n) {
            const int gcol = n0 + wn * 64 + n * 16 + l15;
#pragma unroll
            for (int r = 0; r < 4; ++r)
              outp[(size_t)b * TT * DD + (size_t)(grow + r) * DD + gcol] = f2bf(acc[m][n][r] + bvv[n]);
          }
        }
      } else {
#pragma unroll
        for (int m = 0; m < 4; ++m) {
          const int grow = m0 + wm * 64 + m * 16 + lhi * 4;
#pragma unroll
          for (int n = 0; n < 4; ++n) {
            const int gcol = n0 + wn * 64 + n * 16 + l15;
            u16x4 pk;
#pragma unroll
            for (int r = 0; r < 4; ++r) pk[r] = f2bf(acc[m][n][r] + bvv[n]);
            *(u16x4*)(vtb + (size_t)(b * HH + (gcol >> 6)) * DKH * TT + (size_t)(gcol & 63) * TT + grow) = pk;
          }
        }
      }
    }
  }
  grid.sync();

  // ---------- stage 2: fused attention (256 units; 1/block; waves 0-3 work) ----------
  {
    const int unit = bx;
    const int qt = unit & 3, bh = unit >> 2;
    const int b = bh >> 2, h = bh & 3;
    u16* Klds = (u16*)smem;                  // 16KB
    u16* Vlds = Klds + 128 * 64;             // 16KB
    u16* Plds = Vlds + 64 * 128;             // 32KB
    float* Lred = (float*)(Plds + 128 * 128);  // [2][128]
    const bool act0 = (sub == 0);
    const int len = xlen[b];
    const int nt = (len + 127) >> 7;
    const int lane = tid & 63, wave = tid >> 6;
    const int wm = wave >> 1, wn = wave & 1;
    const int l15 = lane & 15, lhi = lane >> 4;
    const int lr = lane >> 3, lsl = lane & 7;
    const int m0 = qt * 128;
    const u16* qbp = qb + (size_t)b * TT * DD + h * DKH;
    const u16* kbp = kb + (size_t)b * TT * DD + h * DKH;
    const u16* vtp = vtb + (size_t)bh * DKH * TT;
    const float SC = 0.125f * 1.4426950408889634f;

    bf16x8 qf[4][2];
    if (act0) {
#pragma unroll
      for (int m = 0; m < 4; ++m)
#pragma unroll
        for (int ks = 0; ks < 2; ++ks)
          qf[m][ks] = *(const bf16x8*)(qbp + (size_t)(m0 + wm * 64 + m * 16 + l15) * DD + ks * 32 + lhi * 8);
    }
    if (tid512 < 256) ((float*)Lred)[tid512] = 0.f;

    f32x4 oacc[2][4];
#pragma unroll
    for (int i = 0; i < 2; ++i)
#pragma unroll
      for (int j = 0; j < 4; ++j) oacc[i][j] = zero4();

    for (int kt = 0; kt < 4; ++kt) {
      const bool active = act0 && (kt < nt);
      if (active) {
#pragma unroll
        for (int j = 0; j < 4; ++j) {
          const int r = wave * 32 + j * 8 + lr;
          load_lds16(kbp + (size_t)(kt * 128 + r) * DD + ((lsl ^ (r & 7)) << 3),
                     Klds + (wave * 32 + j * 8) * 64);
        }
#pragma unroll
        for (int j = 0; j < 4; ++j) {
          const int rv = wave * 16 + j * 4 + (lane >> 4);
          const int cc = lane & 15;
          load_lds16(vtp + (size_t)rv * TT + kt * 128 + ((cc ^ (rv & 7)) << 3),
                     Vlds + (wave * 16 + j * 4) * 128);
        }
      }
      __syncthreads();
      if (active) {
        f32x4 sacc[4][4];
#pragma unroll
        for (int i = 0; i < 4; ++i)
#pragma unroll
          for (int j = 0; j < 4; ++j) sacc[i][j] = zero4();
#pragma unroll
        for (int ks = 0; ks < 2; ++ks) {
          const int slot = ks * 4 + lhi;
          bf16x8 bfr[4];
#pragma unroll
          for (int n = 0; n < 4; ++n)
            bfr[n] = lds_frag(Klds, wn * 64 + n * 16 + l15, slot);
#pragma unroll
          for (int m = 0; m < 4; ++m)
#pragma unroll
            for (int n = 0; n < 4; ++n)
              sacc[m][n] = __builtin_amdgcn_mfma_f32_16x16x32_bf16(qf[m][ks], bfr[n], sacc[m][n], 0, 0, 0);
        }
        float lsum[4][4];
#pragma unroll
        for (int m = 0; m < 4; ++m)
#pragma unroll
          for (int r = 0; r < 4; ++r) lsum[m][r] = 0.f;
#pragma unroll
        for (int m = 0; m < 4; ++m) {
#pragma unroll
          for (int n = 0; n < 4; ++n) {
            const int col = wn * 64 + n * 16 + l15;
            const bool in = (kt * 128 + col) < len;
#pragma unroll
            for (int r = 0; r < 4; ++r) {
              const int row = wm * 64 + m * 16 + lhi * 4 + r;
              float p = exp2f(sacc[m][n][r] * SC);
              p = in ? p : 0.f;
              lsum[m][r] += p;
              Plds[row * 128 + (col ^ ((row & 7) << 3))] = (u16)(__builtin_bit_cast(unsigned int, p) >> 16);
            }
          }
        }
#pragma unroll
        for (int d = 1; d < 16; d <<= 1)
#pragma unroll
          for (int m = 0; m < 4; ++m)
#pragma unroll
            for (int r = 0; r < 4; ++r) lsum[m][r] += __shfl_xor(lsum[m][r], d);
        if (l15 == 0) {
#pragma unroll
          for (int m = 0; m < 4; ++m)
#pragma unroll
            for (int r = 0; r < 4; ++r)
              Lred[wn * 128 + wm * 64 + m * 16 + lhi * 4 + r] += lsum[m][r];
        }
      }
      __syncthreads();
      if (active) {
#pragma unroll
        for (int ks = 0; ks < 4; ++ks) {
          const int cb = ks * 32 + lhi * 8;
          bf16x8 af[2], bfr[4];
#pragma unroll
          for (int mm = 0; mm < 2; ++mm) {
            const int row = wave * 32 + mm * 16 + l15;
            af[mm] = *(const bf16x8*)(Plds + row * 128 + (cb ^ ((row & 7) << 3)));
          }
#pragma unroll
          for (int n = 0; n < 4; ++n) {
            const int row = n * 16 + l15;
            bfr[n] = *(const bf16x8*)(Vlds + row * 128 + (cb ^ ((row & 7) << 3)));
          }
#pragma unroll
          for (int mm = 0; mm < 2; ++mm)
#pragma unroll
            for (int n = 0; n < 4; ++n)
              oacc[mm][n] = __builtin_amdgcn_mfma_f32_16x16x32_bf16(af[mm], bfr[n], oacc[mm][n], 0, 0, 0);
        }
      }
      __syncthreads();
    }
    if (act0) {
      u16* cb2 = ctx + (size_t)b * TT * DD + h * DKH;
#pragma unroll
      for (int mm = 0; mm < 2; ++mm) {
#pragma unroll
        for (int r = 0; r < 4; ++r) {
          const int row = wave * 32 + mm * 16 + lhi * 4 + r;
          const float linv = 1.0f / (Lred[row] + Lred[128 + row]);
#pragma unroll
          for (int n = 0; n < 4; ++n)
            cb2[(size_t)(m0 + row) * DD + n * 16 + l15] = f2bf(oacc[mm][n][r] * linv);
        }
      }
    }
  }
  grid.sync();

  // ---------- stage 3: h = h0 + ctx@Wo + bo ; hn = LN2(h) ----------
  gemm_ln_stage(ctx, wto, bo, h0, hc, hn, g2, be2, lids, DD, bx, smem, tid512, false);
  grid.sync();

  // ---------- stage 4: ffn = relu(hn@W1 + b1)  (512 units; 2/block) ----------
  {
    const int unit = bx * 2 + sub;   // 0..511, all valid
    u16* Alds = (u16*)(smem + sub * 32768);
    u16* Blds = Alds + 128 * 64;
    const int nx = unit & 7, my = (unit >> 3) & 3, b = unit >> 5;
    const int z = lids[b];
    const int m0 = my * 128, n0 = nx * 128;
    f32x4 acc[4][4];
#pragma unroll
    for (int i = 0; i < 4; ++i)
#pragma unroll
      for (int j = 0; j < 4; ++j) acc[i][j] = zero4();
    gemm128(hn + (size_t)b * TT * DD, wt1 + (size_t)z * FFD * DD, DD, m0, n0,
            Alds, Blds, acc, true, tid);
    const int lane = tid & 63, wave = tid >> 6;
    const int wm = wave >> 1, wn = wave & 1;
    const int l15 = lane & 15, lhi = lane >> 4;
    float bvv[4];
#pragma unroll
    for (int n = 0; n < 4; ++n) bvv[n] = b1[(size_t)z * FFD + n0 + wn * 64 + n * 16 + l15];
#pragma unroll
    for (int m = 0; m < 4; ++m) {
      const int grow = m0 + wm * 64 + m * 16 + lhi * 4;
#pragma unroll
      for (int n = 0; n < 4; ++n) {
        const int gcol = n0 + wn * 64 + n * 16 + l15;
#pragma unroll
        for (int r = 0; r < 4; ++r) {
          float v = acc[m][n][r] + bvv[n];
          ffn[(size_t)b * TT * FFD + (size_t)(grow + r) * FFD + gcol] = f2bf(v > 0.f ? v : 0.f);
        }
      }
    }
  }
  grid.sync();

  // ---------- stage 5: out = LNf(hc + ffn@W2 + b2) ----------
  gemm_ln_stage(ffn, wt2, b2, hc, out, nullptr, gf, bef, lids, FFD, bx, smem, tid512, true);
}

// ---------------- host ----------------
extern "C" void kernel_launch(void* const* d_in, const int* in_sizes, int n_in,
                              void* d_out, int out_size, void* d_ws, size_t ws_size,
                              hipStream_t stream) {
  (void)in_sizes; (void)n_in; (void)out_size; (void)ws_size;
  const float* x    = (const float*)d_in[0];
  const int*   xlen = (const int*)d_in[1];
  const int*   lids = (const int*)d_in[2];
  const float* Wq = (const float*)d_in[3];
  const float* bq = (const float*)d_in[4];
  const float* Wk = (const float*)d_in[5];
  const float* bk = (const float*)d_in[6];
  const float* Wv = (const float*)d_in[7];
  const float* bv = (const float*)d_in[8];
  const float* Wo = (const float*)d_in[9];
  const float* bo = (const float*)d_in[10];
  const float* W1 = (const float*)d_in[11];
  const float* b1 = (const float*)d_in[12];
  const float* W2 = (const float*)d_in[13];
  const float* b2 = (const float*)d_in[14];
  const float* g1 = (const float*)d_in[15];
  const float* be1= (const float*)d_in[16];
  const float* g2 = (const float*)d_in[17];
  const float* be2= (const float*)d_in[18];
  const float* gf = (const float*)d_in[19];
  const float* bef= (const float*)d_in[20];

  char* ws = (char*)d_ws;
  size_t off = 0;
  auto alloc = [&](size_t bytes) -> void* {
    void* p = ws + off;
    off = (off + bytes + 255) & ~(size_t)255;
    return p;
  };
  u16* wtq = (u16*)alloc((size_t)NLANG * DD * DD * 2);
  u16* wtk = (u16*)alloc((size_t)NLANG * DD * DD * 2);
  u16* wtv = (u16*)alloc((size_t)NLANG * DD * DD * 2);
  u16* wto = (u16*)alloc((size_t)NLANG * DD * DD * 2);
  u16* wt1 = (u16*)alloc((size_t)NLANG * DD * FFD * 2);
  u16* wt2 = (u16*)alloc((size_t)NLANG * FFD * DD * 2);
  u16* h0  = (u16*)alloc((size_t)NB * TT * DD * 2);
  u16* hc  = (u16*)alloc((size_t)NB * TT * DD * 2);
  u16* hn  = (u16*)alloc((size_t)NB * TT * DD * 2);
  u16* qb  = (u16*)alloc((size_t)NB * TT * DD * 2);
  u16* kb  = (u16*)alloc((size_t)NB * TT * DD * 2);
  u16* vtb = (u16*)alloc((size_t)NB * TT * DD * 2);
  u16* ctx = (u16*)alloc((size_t)NB * TT * DD * 2);
  u16* ffn = (u16*)alloc((size_t)NB * TT * FFD * 2);
  float* outp = (float*)d_out;

  void* args[] = {
    (void*)&x, (void*)&xlen, (void*)&lids,
    (void*)&Wq, (void*)&bq, (void*)&Wk, (void*)&bk,
    (void*)&Wv, (void*)&bv, (void*)&Wo, (void*)&bo,
    (void*)&W1, (void*)&b1, (void*)&W2, (void*)&b2,
    (void*)&g1, (void*)&be1, (void*)&g2, (void*)&be2,
    (void*)&gf, (void*)&bef,
    (void*)&wtq, (void*)&wtk, (void*)&wtv, (void*)&wto, (void*)&wt1, (void*)&wt2,
    (void*)&h0, (void*)&hc, (void*)&hn, (void*)&qb, (void*)&kb, (void*)&vtb,
    (void*)&ctx, (void*)&ffn, (void*)&outp
  };
  hipLaunchCooperativeKernel((const void*)mega_kernel, dim3(256), dim3(512),
                             args, 0, stream);
}